// Round 17
// baseline (119.682 us; speedup 1.0000x reference)
//
#include <hip/hip_runtime.h>
#include <hip/hip_bf16.h>
#include <cstdint>
#include <type_traits>

#define DM 1024
#define HEADS 16
#define DH 64
#define SEQ 2048
#define BATCH 2

typedef __attribute__((ext_vector_type(8))) short bf16x8;
typedef __attribute__((ext_vector_type(4))) float f32x4;
typedef __attribute__((ext_vector_type(16))) float f32x16;
typedef __attribute__((ext_vector_type(2))) unsigned int u32x2;
typedef __attribute__((ext_vector_type(4))) unsigned int u32x4;

#define SCALE2 0.18033688011112042f   /* (1/8)*log2(e) */

#define GLOAD(dst, ptr) \
    asm volatile("global_load_dwordx4 %0, %1, off" : "=v"(dst) : "v"(ptr) : "memory")

static __device__ __forceinline__ unsigned short f2bf(float f) {
    unsigned u = __builtin_bit_cast(unsigned, f);
    u = u + 0x7fffu + ((u >> 16) & 1u);
    return (unsigned short)(u >> 16);
}
static __device__ __forceinline__ float bf2f(unsigned short us) {
    return __builtin_bit_cast(float, (unsigned)us << 16);
}

// ---------------- fused cast fp32 -> bf16, all 6 tensors in one launch ----------------
__global__ __launch_bounds__(256) void cast_all_k(
    const float* __restrict__ q, const float* __restrict__ kv,
    const float* __restrict__ wq, const float* __restrict__ wk,
    const float* __restrict__ wv, const float* __restrict__ wo,
    unsigned short* __restrict__ qb, unsigned short* __restrict__ kvb,
    unsigned short* __restrict__ wqb, unsigned short* __restrict__ wkb,
    unsigned short* __restrict__ wvb, unsigned short* __restrict__ wob)
{
    int blk = blockIdx.x;
    const float* s; unsigned short* d; int base;
    if (blk < 2048)      { s = q;  d = qb;  base = 0; }
    else if (blk < 4096) { s = kv; d = kvb; base = 2048; }
    else if (blk < 4608) { s = wq; d = wqb; base = 4096; }
    else if (blk < 5120) { s = wk; d = wkb; base = 4608; }
    else if (blk < 5632) { s = wv; d = wvb; base = 5120; }
    else                 { s = wo; d = wob; base = 5632; }
    int i = ((blk - base) * 256 + threadIdx.x) * 8;
    float4 a = *(const float4*)(s + i);
    float4 b2 = *(const float4*)(s + i + 4);
    ushort4 o0, o1;
    o0.x = f2bf(a.x);  o0.y = f2bf(a.y);  o0.z = f2bf(a.z);  o0.w = f2bf(a.w);
    o1.x = f2bf(b2.x); o1.y = f2bf(b2.y); o1.z = f2bf(b2.z); o1.w = f2bf(b2.w);
    *(ushort4*)(d + i) = o0;
    *(ushort4*)(d + i + 4) = o1;
}

// ---------------- merged QKV projection: 128x128 m97-style tile, NT vs [Wq;Wk;Wv] ----------------
// grid (32, 24): m0 = bx*128, n0 = by*128. Region: by<8 -> Q (A=qb, out Qp scaled);
// by<16 -> K (A=kvb, Kp row-major); else V (A=kvb, Vt transposed).
// 4 waves, wave w owns 64x64 quadrant (wm,wn), 4x4 frags of 16x16x32.
__global__ __launch_bounds__(256) void proj_qkv(
    const unsigned short* __restrict__ qb,
    const unsigned short* __restrict__ kvb,
    const unsigned short* __restrict__ Wall,
    const float* __restrict__ bq, const float* __restrict__ bk, const float* __restrict__ bv,
    unsigned short* __restrict__ Qp, unsigned short* __restrict__ Kp,
    unsigned short* __restrict__ Vt)
{
    constexpr int BK = 64, K = 1024;
    __shared__ alignas(16) unsigned short As[128 * BK];
    __shared__ alignas(16) unsigned short Bs[128 * BK];

    const int t = threadIdx.x;
    const int lane = t & 63;
    const int w = t >> 6;
    const int wm = (w >> 1) * 64, wn = (w & 1) * 64;
    const int lr = lane & 15, lg = lane >> 4;
    const int m0 = blockIdx.x * 128, n0 = blockIdx.y * 128;
    const int region = (blockIdx.y >= 8) + (blockIdx.y >= 16);   // 0=Q 1=K 2=V
    const unsigned short* A = (region == 0) ? qb : kvb;

    f32x4 acc[4][4] = {};
    const int srow = t >> 3;       // 0..31
    const int schunk = t & 7;      // 16B chunk within 128B row

    for (int kt = 0; kt < K; kt += BK) {
#pragma unroll
        for (int c = 0; c < 4; c++) {
            int row = srow + c * 32;
            int gc = schunk ^ (row & 7);
            __builtin_amdgcn_global_load_lds(
                (const __attribute__((address_space(1))) unsigned int*)(A + (size_t)(m0 + row) * K + kt + gc * 8),
                (__attribute__((address_space(3))) unsigned int*)(&As[row * BK + schunk * 8]), 16, 0, 0);
            __builtin_amdgcn_global_load_lds(
                (const __attribute__((address_space(1))) unsigned int*)(Wall + (size_t)(n0 + row) * K + kt + gc * 8),
                (__attribute__((address_space(3))) unsigned int*)(&Bs[row * BK + schunk * 8]), 16, 0, 0);
        }
        __syncthreads();
#pragma unroll
        for (int kk = 0; kk < 2; kk++) {
            bf16x8 af[4], bfr[4];
#pragma unroll
            for (int i = 0; i < 4; i++) {
                int rowA = wm + i * 16 + lr;
                af[i] = *(const bf16x8*)(&As[rowA * BK + (((kk * 4 + lg) ^ (rowA & 7))) * 8]);
                int rowB = wn + i * 16 + lr;
                bfr[i] = *(const bf16x8*)(&Bs[rowB * BK + (((kk * 4 + lg) ^ (rowB & 7))) * 8]);
            }
#pragma unroll
            for (int i = 0; i < 4; i++)
#pragma unroll
                for (int j = 0; j < 4; j++)
                    acc[i][j] = __builtin_amdgcn_mfma_f32_16x16x32_bf16(af[i], bfr[j], acc[i][j], 0, 0, 0);
        }
        __syncthreads();
    }

    if (region == 0) {
#pragma unroll
        for (int i = 0; i < 4; i++) {
            int rbase = m0 + wm + i * 16 + lg * 4;
#pragma unroll
            for (int j = 0; j < 4; j++) {
                int col = n0 + wn + j * 16 + lr;
                float bvv = bq[col];
#pragma unroll
                for (int r = 0; r < 4; r++)
                    Qp[(size_t)(rbase + r) * 1024 + col] = f2bf((acc[i][j][r] + bvv) * SCALE2);
            }
        }
    } else if (region == 1) {
#pragma unroll
        for (int i = 0; i < 4; i++) {
            int rbase = m0 + wm + i * 16 + lg * 4;
#pragma unroll
            for (int j = 0; j < 4; j++) {
                int col = n0 - 1024 + wn + j * 16 + lr;
                float bvv = bk[col];
#pragma unroll
                for (int r = 0; r < 4; r++)
                    Kp[(size_t)(rbase + r) * 1024 + col] = f2bf(acc[i][j][r] + bvv);
            }
        }
    } else {
        int bidx = m0 >> 11;
#pragma unroll
        for (int i = 0; i < 4; i++) {
            int s0 = (m0 & 2047) + wm + i * 16 + lg * 4;
#pragma unroll
            for (int j = 0; j < 4; j++) {
                int nv = n0 - 2048 + wn + j * 16 + lr;
                float bvv = bv[nv];
                int hh = nv >> 6, dd = nv & 63;
                ushort4 st;
                st.x = f2bf(acc[i][j][0] + bvv);
                st.y = f2bf(acc[i][j][1] + bvv);
                st.z = f2bf(acc[i][j][2] + bvv);
                st.w = f2bf(acc[i][j][3] + bvv);
                *(ushort4*)(Vt + ((size_t)((bidx * HEADS + hh) * DH + dd)) * SEQ + s0) = st;
            }
        }
    }
}

// ---------------- O projection: NT GEMM 64x128, fp32 out ----------------
__global__ __launch_bounds__(256) void gemm_o(
    const unsigned short* __restrict__ A,
    const unsigned short* __restrict__ Bw,
    const float* __restrict__ bias,
    float* __restrict__ C,
    int M, int N, int K)
{
    constexpr int BK = 64;
    __shared__ alignas(16) unsigned short As[64 * BK];
    __shared__ alignas(16) unsigned short Bs[128 * BK];

    const int t = threadIdx.x;
    const int lane = t & 63;
    const int w = t >> 6;
    const int wn = w * 32;
    const int lr = lane & 15, lg = lane >> 4;
    const int m0 = blockIdx.x * 64, n0 = blockIdx.y * 128;

    f32x4 acc[4][2] = {};
    const int srow = t >> 3;
    const int schunk = t & 7;

    for (int kt = 0; kt < K; kt += BK) {
#pragma unroll
        for (int c = 0; c < 2; c++) {
            int row = srow + c * 32;
            int gc = schunk ^ (row & 7);
            __builtin_amdgcn_global_load_lds(
                (const __attribute__((address_space(1))) unsigned int*)(A + (size_t)(m0 + row) * K + kt + gc * 8),
                (__attribute__((address_space(3))) unsigned int*)(&As[row * BK + schunk * 8]), 16, 0, 0);
        }
#pragma unroll
        for (int c = 0; c < 4; c++) {
            int row = srow + c * 32;
            int gc = schunk ^ (row & 7);
            __builtin_amdgcn_global_load_lds(
                (const __attribute__((address_space(1))) unsigned int*)(Bw + (size_t)(n0 + row) * K + kt + gc * 8),
                (__attribute__((address_space(3))) unsigned int*)(&Bs[row * BK + schunk * 8]), 16, 0, 0);
        }
        __syncthreads();
#pragma unroll
        for (int kk = 0; kk < 2; kk++) {
            bf16x8 af[4], bfr[2];
#pragma unroll
            for (int i = 0; i < 4; i++)
                af[i] = *(const bf16x8*)(&As[(i * 16 + lr) * BK + (((kk * 4 + lg) ^ (lr & 7))) * 8]);
#pragma unroll
            for (int jj = 0; jj < 2; jj++)
                bfr[jj] = *(const bf16x8*)(&Bs[(wn + jj * 16 + lr) * BK + (((kk * 4 + lg) ^ (lr & 7))) * 8]);
#pragma unroll
            for (int i = 0; i < 4; i++)
#pragma unroll
                for (int jj = 0; jj < 2; jj++)
                    acc[i][jj] = __builtin_amdgcn_mfma_f32_16x16x32_bf16(af[i], bfr[jj], acc[i][jj], 0, 0, 0);
        }
        __syncthreads();
    }

#pragma unroll
    for (int i = 0; i < 4; i++) {
        int rbase = m0 + i * 16 + lg * 4;
#pragma unroll
        for (int jj = 0; jj < 2; jj++) {
            int col = n0 + wn + jj * 16 + lr;
            float bvv = bias[col];
#pragma unroll
            for (int r = 0; r < 4; r++)
                C[(size_t)(rbase + r) * 1024 + col] = acc[i][jj][r] + bvv;
        }
    }
}

// ---------------- causal flash attention: SPLIT-K, 3-buffer LDS, 1 barrier/iter ----------------
// (unchanged from R16 — measured 39.9 us, passing)
__global__ __launch_bounds__(256, 2) void attn_k(
    const unsigned short* __restrict__ Qp,
    const unsigned short* __restrict__ Kp,
    const unsigned short* __restrict__ Vt,
    unsigned short* __restrict__ Ctx,
    unsigned short* __restrict__ pO,     // [32 bh][36 slots][128 q][64 d] bf16 (raw O)
    float2* __restrict__ pML)            // [32 bh][36 slots][128 q] (m, l)
{
    __shared__ alignas(16) unsigned char ldsb[3 * 16384];   // 3 x [K 8KB | V 8KB]

    const int lane = threadIdx.x & 63;
    const int w = threadIdx.x >> 6;          // 0..3
    const int x = blockIdx.x;
    const int bh = x & 31;
    const int g = 39 - (x >> 5);             // LPT: long parts first
    int c, p, S;
    if (g < 4)       { c = g;                    p = 0;            S = 1; }
    else if (g < 12) { c = 4 + ((g - 4) >> 1);   p = (g - 4) & 1;  S = 2; }
    else if (g < 24) { c = 8 + (g - 12) / 3;     p = (g - 12) % 3; S = 3; }
    else             { c = 12 + ((g - 24) >> 2); p = (g - 24) & 3; S = 4; }
    const int nb = 2 * c + 2;
    const int len0 = (nb + S - 1) / S;
    const int start = p * len0;
    const int len = min(len0, nb - start);

    const int b = bh >> 4, h = bh & 15;
    const int q0 = c * 128;
    const int lq = lane & 31;
    const int hi = lane >> 5;
    const int qq = q0 + w * 32 + lq;
    const int my_nb = (q0 + 32 * w + 95) >> 6;   // global causal tile bound for this wave
    const int qmin = q0 + 32 * w;                // wave-uniform smallest q row
    constexpr float THR = 11.5f;

    // Q via asm loads + full drain: compiler's VMEM FIFO then tracks ONLY staging loads
    bf16x8 Qf[4];
    {
        u32x4 qtmp[4];
        const unsigned short* qbp = Qp + (size_t)(b * SEQ + qq) * DM + h * DH + hi * 8;
#pragma unroll
        for (int d = 0; d < 4; d++) GLOAD(qtmp[d], qbp + d * 16);
        asm volatile("s_waitcnt vmcnt(0)" ::: "memory");
        __builtin_amdgcn_sched_barrier(0);
#pragma unroll
        for (int d = 0; d < 4; d++) Qf[d] = __builtin_bit_cast(bf16x8, qtmp[d]);
    }

    // staging source addresses (pre-swizzled involution, rule 21)
    const int colx = (((lane & 7) ^ (lane >> 3)) << 4);
    const char* kg[2];
    const char* vg[2];
#pragma unroll
    for (int u = 0; u < 2; u++) {
        int s = 2 * w + u;
        int row = 8 * s + (lane >> 3);
        kg[u] = (const char*)Kp + (((size_t)(b * SEQ + row) * DM + h * DH) * 2) + colx;
        vg[u] = (const char*)Vt + ((((size_t)(b * HEADS + h) * DH + row) * SEQ) * 2) + colx;
    }
    const int kxor = (lq & 7) << 4;

    auto stage = [&](int buf, int t) {
        int kboff_k = t * (64 * DM * 2);    // K advances 64 rows
        int kboff_v = t * 128;              // V advances 64 kv cols (bytes)
#pragma unroll
        for (int u = 0; u < 2; u++) {
            int s = 2 * w + u;
            __builtin_amdgcn_global_load_lds(
                (const __attribute__((address_space(1))) unsigned int*)(kg[u] + kboff_k),
                (__attribute__((address_space(3))) unsigned int*)(&ldsb[buf * 16384 + s * 1024 + lane * 16]), 16, 0, 0);
            __builtin_amdgcn_global_load_lds(
                (const __attribute__((address_space(1))) unsigned int*)(vg[u] + kboff_v),
                (__attribute__((address_space(3))) unsigned int*)(&ldsb[buf * 16384 + 8192 + s * 1024 + lane * 16]), 16, 0, 0);
        }
    };

    f32x16 o0 = {}, o1 = {};
    float m_run = -1e30f, l_run = 0.f;
    const int qmh0 = qq - 4 * hi;

    stage(0, start);                       // prologue: depth-2 prefetch
    if (len > 1) stage(1, start + 1);

    for (int it = 0; it < len; it++) {
        const int t = start + it;
        const int cur = it % 3;
        if (it + 1 < len) { asm volatile("s_waitcnt vmcnt(4)" ::: "memory"); }
        else              { asm volatile("s_waitcnt vmcnt(0)" ::: "memory"); }
        __builtin_amdgcn_sched_barrier(0);
        __builtin_amdgcn_s_barrier();
        if (it + 2 < len) stage((it + 2) % 3, t + 2);

        if (t < my_nb) {
            const unsigned char* Kb = &ldsb[cur * 16384];
            const unsigned char* Vb = Kb + 8192;
            const int kb = t * 64;

            bf16x8 KA[4], KB[4], Vc[4][2];
#pragma unroll
            for (int d = 0; d < 4; d++) {
                int col = (d * 32 + hi * 16) ^ kxor;
                KA[d] = *(const bf16x8*)(Kb + lq * 128 + col);
                KB[d] = *(const bf16x8*)(Kb + (lq + 32) * 128 + col);
            }
#pragma unroll
            for (int s = 0; s < 4; s++)
#pragma unroll
                for (int dt = 0; dt < 2; dt++)
                    Vc[s][dt] = *(const bf16x8*)(Vb + (dt * 32 + lq) * 128 + ((s * 32 + hi * 16) ^ kxor));

            f32x16 sa0 = {}, sa1 = {};
            __builtin_amdgcn_s_setprio(1);
#pragma unroll
            for (int d = 0; d < 4; d++) {
                sa0 = __builtin_amdgcn_mfma_f32_32x32x16_bf16(KA[d], Qf[d], sa0, 0, 0, 0);
                sa1 = __builtin_amdgcn_mfma_f32_32x32x16_bf16(KB[d], Qf[d], sa1, 0, 0, 0);
            }
            __builtin_amdgcn_s_setprio(0);

            if (kb + 63 > qmin) {
                const int qmh = qmh0 - kb;
#pragma unroll
                for (int r = 0; r < 16; r++) {
                    int kvl = (r & 3) + 8 * (r >> 2);
                    sa0[r] = (kvl <= qmh) ? sa0[r] : -1e30f;
                    sa1[r] = (kvl + 32 <= qmh) ? sa1[r] : -1e30f;
                }
            }
            float mx[16];
#pragma unroll
            for (int r = 0; r < 16; r++) mx[r] = fmaxf(sa0[r], sa1[r]);
#pragma unroll
            for (int r = 0; r < 8; r++) mx[r] = fmaxf(mx[r], mx[r + 8]);
#pragma unroll
            for (int r = 0; r < 4; r++) mx[r] = fmaxf(mx[r], mx[r + 4]);
            mx[0] = fmaxf(mx[0], mx[2]);
            mx[1] = fmaxf(mx[1], mx[3]);
            float mloc = fmaxf(mx[0], mx[1]);
            mloc = fmaxf(mloc, __shfl_xor(mloc, 32));

            if (!__all(mloc - m_run <= THR)) {
                float m_new = fmaxf(m_run, mloc);
                float sf = __builtin_amdgcn_exp2f(m_run - m_new);
                l_run *= sf;
#pragma unroll
                for (int r = 0; r < 16; r++) { o0[r] *= sf; o1[r] *= sf; }
                m_run = m_new;
            }

            float p0v[16], p1v[16];
#pragma unroll
            for (int r = 0; r < 16; r++) {
                p0v[r] = __builtin_amdgcn_exp2f(sa0[r] - m_run);
                p1v[r] = __builtin_amdgcn_exp2f(sa1[r] - m_run);
            }
            float s4[8];
#pragma unroll
            for (int r = 0; r < 8; r++) s4[r] = (p0v[r] + p0v[r + 8]) + (p1v[r] + p1v[r + 8]);
#pragma unroll
            for (int r = 0; r < 4; r++) s4[r] += s4[r + 4];
            float ps = (s4[0] + s4[1]) + (s4[2] + s4[3]);
            ps += __shfl_xor(ps, 32);
            l_run += ps;

            unsigned c0[8], c1[8];
#pragma unroll
            for (int ii = 0; ii < 8; ii++) {
                unsigned pk;
                asm("v_cvt_pk_bf16_f32 %0, %1, %2" : "=v"(pk) : "v"(p0v[2 * ii]), "v"(p0v[2 * ii + 1]));
                c0[ii] = pk;
                asm("v_cvt_pk_bf16_f32 %0, %1, %2" : "=v"(pk) : "v"(p1v[2 * ii]), "v"(p1v[2 * ii + 1]));
                c1[ii] = pk;
            }
            bf16x8 Pb[4];
            {
                u32x2 r02 = __builtin_amdgcn_permlane32_swap(c0[0], c0[2], false, false);
                u32x2 r13 = __builtin_amdgcn_permlane32_swap(c0[1], c0[3], false, false);
                u32x2 r46 = __builtin_amdgcn_permlane32_swap(c0[4], c0[6], false, false);
                u32x2 r57 = __builtin_amdgcn_permlane32_swap(c0[5], c0[7], false, false);
                u32x4 w0 = {r02.x, r13.x, r02.y, r13.y};
                u32x4 w1 = {r46.x, r57.x, r46.y, r57.y};
                Pb[0] = __builtin_bit_cast(bf16x8, w0);
                Pb[1] = __builtin_bit_cast(bf16x8, w1);
            }
            {
                u32x2 r02 = __builtin_amdgcn_permlane32_swap(c1[0], c1[2], false, false);
                u32x2 r13 = __builtin_amdgcn_permlane32_swap(c1[1], c1[3], false, false);
                u32x2 r46 = __builtin_amdgcn_permlane32_swap(c1[4], c1[6], false, false);
                u32x2 r57 = __builtin_amdgcn_permlane32_swap(c1[5], c1[7], false, false);
                u32x4 w0 = {r02.x, r13.x, r02.y, r13.y};
                u32x4 w1 = {r46.x, r57.x, r46.y, r57.y};
                Pb[2] = __builtin_bit_cast(bf16x8, w0);
                Pb[3] = __builtin_bit_cast(bf16x8, w1);
            }

            __builtin_amdgcn_s_setprio(1);
#pragma unroll
            for (int s = 0; s < 4; s++) {
                o0 = __builtin_amdgcn_mfma_f32_32x32x16_bf16(Vc[s][0], Pb[s], o0, 0, 0, 0);
                o1 = __builtin_amdgcn_mfma_f32_32x32x16_bf16(Vc[s][1], Pb[s], o1, 0, 0, 0);
            }
            __builtin_amdgcn_s_setprio(0);
        }
    }

    if (S == 1) {
        float inv = 1.0f / l_run;
        unsigned short* cb = Ctx + (size_t)(b * SEQ + qq) * DM + h * DH + hi * 4;
#pragma unroll
        for (int gg = 0; gg < 4; gg++) {
            ushort4 s0, s1;
            s0.x = f2bf(o0[4 * gg + 0] * inv); s0.y = f2bf(o0[4 * gg + 1] * inv);
            s0.z = f2bf(o0[4 * gg + 2] * inv); s0.w = f2bf(o0[4 * gg + 3] * inv);
            s1.x = f2bf(o1[4 * gg + 0] * inv); s1.y = f2bf(o1[4 * gg + 1] * inv);
            s1.z = f2bf(o1[4 * gg + 2] * inv); s1.w = f2bf(o1[4 * gg + 3] * inv);
            *(ushort4*)(cb + gg * 8) = s0;
            *(ushort4*)(cb + 32 + gg * 8) = s1;
        }
        return;
    }

    const int slot = g - 4;                       // 0..35
    const int qrow = w * 32 + lq;
    unsigned short* pb = pO + ((size_t)(bh * 36 + slot) * 8192) + qrow * 64 + hi * 4;
#pragma unroll
    for (int gg = 0; gg < 4; gg++) {
        ushort4 s0, s1;
        s0.x = f2bf(o0[4 * gg + 0]); s0.y = f2bf(o0[4 * gg + 1]);
        s0.z = f2bf(o0[4 * gg + 2]); s0.w = f2bf(o0[4 * gg + 3]);
        s1.x = f2bf(o1[4 * gg + 0]); s1.y = f2bf(o1[4 * gg + 1]);
        s1.z = f2bf(o1[4 * gg + 2]); s1.w = f2bf(o1[4 * gg + 3]);
        *(ushort4*)(pb + gg * 8) = s0;
        *(ushort4*)(pb + 32 + gg * 8) = s1;
    }
    if (hi == 0)
        pML[(size_t)(bh * 36 + slot) * 128 + qrow] = make_float2(m_run, l_run);
}

// ---------------- split-K combine: Ctx[c=4..15] = weighted sum of partials ----------------
__global__ __launch_bounds__(256) void combine_k(
    const unsigned short* __restrict__ pO,
    const float2* __restrict__ pML,
    unsigned short* __restrict__ Ctx)
{
    const int x = blockIdx.x;
    const int bh = x & 31;
    const int c = (x >> 5) + 4;              // 4..15
    const int S = (c >> 2) + 1;              // 2..4
    int slot0;
    if (c < 8)       slot0 = 2 * (c - 4);
    else if (c < 12) slot0 = 8 + 3 * (c - 8);
    else             slot0 = 20 + 4 * (c - 12);
    const int b = bh >> 4, h = bh & 15;

    const int q = threadIdx.x >> 1;          // 0..127
    const int d0 = (threadIdx.x & 1) * 32;

    float m[4], l[4], wgt[4];
    float M = -1e30f;
#pragma unroll
    for (int i = 0; i < 4; i++) {
        if (i < S) {
            float2 ml = pML[(size_t)(bh * 36 + slot0 + i) * 128 + q];
            m[i] = ml.x; l[i] = ml.y;
            M = fmaxf(M, m[i]);
        }
    }
    float L = 0.f;
#pragma unroll
    for (int i = 0; i < 4; i++) {
        if (i < S) {
            wgt[i] = __builtin_amdgcn_exp2f(m[i] - M);
            L += l[i] * wgt[i];
        }
    }
    float invL = 1.0f / L;
#pragma unroll
    for (int i = 0; i < 4; i++) if (i < S) wgt[i] *= invL;

    unsigned short* cb = Ctx + (size_t)(b * SEQ + c * 128 + q) * DM + h * DH + d0;
#pragma unroll
    for (int dd = 0; dd < 32; dd += 8) {
        float acc[8] = {};
#pragma unroll
        for (int i = 0; i < 4; i++) {
            if (i < S) {
                const unsigned short* pp = pO + ((size_t)(bh * 36 + slot0 + i) * 8192) + q * 64 + d0 + dd;
                bf16x8 v = *(const bf16x8*)pp;
#pragma unroll
                for (int e = 0; e < 8; e++)
                    acc[e] += wgt[i] * bf2f((unsigned short)v[e]);
            }
        }
        ushort4 s0, s1;
        s0.x = f2bf(acc[0]); s0.y = f2bf(acc[1]); s0.z = f2bf(acc[2]); s0.w = f2bf(acc[3]);
        s1.x = f2bf(acc[4]); s1.y = f2bf(acc[5]); s1.z = f2bf(acc[6]); s1.w = f2bf(acc[7]);
        *(ushort4*)(cb + dd) = s0;
        *(ushort4*)(cb + dd + 4) = s1;
    }
}

extern "C" void kernel_launch(void* const* d_in, const int* in_sizes, int n_in,
                              void* d_out, int out_size, void* d_ws, size_t ws_size,
                              hipStream_t stream)
{
    const float* query = (const float*)d_in[0];
    const float* keyv  = (const float*)d_in[1];
    const float* Wq = (const float*)d_in[2];
    const float* bq = (const float*)d_in[3];
    const float* Wk = (const float*)d_in[4];
    const float* bk = (const float*)d_in[5];
    const float* Wv = (const float*)d_in[6];
    const float* bv = (const float*)d_in[7];
    const float* Wo = (const float*)d_in[8];
    const float* bo = (const float*)d_in[9];
    float* out = (float*)d_out;

    const int M = BATCH * SEQ;
    char* ws = (char*)d_ws;
    size_t off = 0;
    auto alloc = [&](size_t elems) { unsigned short* p = (unsigned short*)(ws + off); off += elems * 2; return p; };
    unsigned short* qb  = alloc((size_t)M * DM);    // dead after proj -> reused as pO
    unsigned short* kvb = alloc((size_t)M * DM);    // dead after proj -> reused as pO
    unsigned short* wqb = alloc((size_t)DM * DM);   // wqb/wkb/wvb MUST stay contiguous (merged QKV weight block)
    unsigned short* wkb = alloc((size_t)DM * DM);
    unsigned short* wvb = alloc((size_t)DM * DM);   // dead after proj -> reused as pML
    unsigned short* wob = alloc((size_t)DM * DM);
    unsigned short* Qp  = alloc((size_t)M * DM);
    unsigned short* Kp  = alloc((size_t)M * DM);
    unsigned short* Vt  = alloc((size_t)M * DM);
    unsigned short* Ctx = alloc((size_t)M * DM);

    // split-K scratch overlaid on buffers that are dead by attn time
    unsigned short* pO  = (unsigned short*)(ws + 0);            // 18,874,368 B (qb+kvb+wqb exactly)
    float2*         pML = (float2*)(ws + 20971520);             // wvb start, 1.125 MB

    cast_all_k<<<6144, 256, 0, stream>>>(query, keyv, Wq, Wk, Wv, Wo,
                                         qb, kvb, wqb, wkb, wvb, wob);

    proj_qkv<<<dim3(M / 128, 24), 256, 0, stream>>>(qb, kvb, wqb, bq, bk, bv, Qp, Kp, Vt);

    attn_k<<<dim3(1280), 256, 0, stream>>>(Qp, Kp, Vt, Ctx, pO, pML);
    combine_k<<<dim3(384), 256, 0, stream>>>(pO, pML, Ctx);

    gemm_o<<<dim3(M / 64, 8), 256, 0, stream>>>(Ctx, wob, bo, out, M, DM, DM);
}

// Round 18
// 111.905 us; speedup vs baseline: 1.0695x; 1.0695x over previous
//
#include <hip/hip_runtime.h>
#include <hip/hip_bf16.h>
#include <cstdint>
#include <type_traits>

#define DM 1024
#define HEADS 16
#define DH 64
#define SEQ 2048
#define BATCH 2

typedef __attribute__((ext_vector_type(8))) short bf16x8;
typedef __attribute__((ext_vector_type(4))) float f32x4;
typedef __attribute__((ext_vector_type(16))) float f32x16;
typedef __attribute__((ext_vector_type(2))) unsigned int u32x2;
typedef __attribute__((ext_vector_type(4))) unsigned int u32x4;

#define SCALE2 0.18033688011112042f   /* (1/8)*log2(e) */

#define GLOAD(dst, ptr) \
    asm volatile("global_load_dwordx4 %0, %1, off" : "=v"(dst) : "v"(ptr) : "memory")

static __device__ __forceinline__ unsigned short f2bf(float f) {
    unsigned u = __builtin_bit_cast(unsigned, f);
    u = u + 0x7fffu + ((u >> 16) & 1u);
    return (unsigned short)(u >> 16);
}
static __device__ __forceinline__ float bf2f(unsigned short us) {
    return __builtin_bit_cast(float, (unsigned)us << 16);
}

// ---------------- fused cast fp32 -> bf16, all 6 tensors in one launch ----------------
__global__ __launch_bounds__(256) void cast_all_k(
    const float* __restrict__ q, const float* __restrict__ kv,
    const float* __restrict__ wq, const float* __restrict__ wk,
    const float* __restrict__ wv, const float* __restrict__ wo,
    unsigned short* __restrict__ qb, unsigned short* __restrict__ kvb,
    unsigned short* __restrict__ wqb, unsigned short* __restrict__ wkb,
    unsigned short* __restrict__ wvb, unsigned short* __restrict__ wob)
{
    int blk = blockIdx.x;
    const float* s; unsigned short* d; int base;
    if (blk < 2048)      { s = q;  d = qb;  base = 0; }
    else if (blk < 4096) { s = kv; d = kvb; base = 2048; }
    else if (blk < 4608) { s = wq; d = wqb; base = 4096; }
    else if (blk < 5120) { s = wk; d = wkb; base = 4608; }
    else if (blk < 5632) { s = wv; d = wvb; base = 5120; }
    else                 { s = wo; d = wob; base = 5632; }
    int i = ((blk - base) * 256 + threadIdx.x) * 8;
    float4 a = *(const float4*)(s + i);
    float4 b2 = *(const float4*)(s + i + 4);
    ushort4 o0, o1;
    o0.x = f2bf(a.x);  o0.y = f2bf(a.y);  o0.z = f2bf(a.z);  o0.w = f2bf(a.w);
    o1.x = f2bf(b2.x); o1.y = f2bf(b2.y); o1.z = f2bf(b2.z); o1.w = f2bf(b2.w);
    *(ushort4*)(d + i) = o0;
    *(ushort4*)(d + i + 4) = o1;
}

// ---------------- merged QKV projection: one NT GEMM vs [Wq;Wk;Wv] (N=3072) ----------------
__global__ __launch_bounds__(256) void proj_qkv(
    const unsigned short* __restrict__ qb,
    const unsigned short* __restrict__ kvb,
    const unsigned short* __restrict__ Wall,
    const float* __restrict__ bq, const float* __restrict__ bk, const float* __restrict__ bv,
    unsigned short* __restrict__ Qp, unsigned short* __restrict__ Kp,
    unsigned short* __restrict__ Vt)
{
    constexpr int BK = 64, K = 1024;
    __shared__ alignas(16) unsigned short As[64 * BK];
    __shared__ alignas(16) unsigned short Bs[128 * BK];

    const int t = threadIdx.x;
    const int lane = t & 63;
    const int w = t >> 6;
    const int wn = w * 32;
    const int lr = lane & 15, lg = lane >> 4;
    const int m0 = blockIdx.x * 64, n0 = blockIdx.y * 128;
    const int region = (blockIdx.y >= 8) + (blockIdx.y >= 16);   // 0=Q 1=K 2=V
    const unsigned short* A = (region == 0) ? qb : kvb;

    f32x4 acc[4][2] = {};
    const int srow = t >> 3;
    const int schunk = t & 7;

    for (int kt = 0; kt < K; kt += BK) {
#pragma unroll
        for (int c = 0; c < 2; c++) {
            int row = srow + c * 32;
            int gc = schunk ^ (row & 7);
            __builtin_amdgcn_global_load_lds(
                (const __attribute__((address_space(1))) unsigned int*)(A + (size_t)(m0 + row) * K + kt + gc * 8),
                (__attribute__((address_space(3))) unsigned int*)(&As[row * BK + schunk * 8]), 16, 0, 0);
        }
#pragma unroll
        for (int c = 0; c < 4; c++) {
            int row = srow + c * 32;
            int gc = schunk ^ (row & 7);
            __builtin_amdgcn_global_load_lds(
                (const __attribute__((address_space(1))) unsigned int*)(Wall + (size_t)(n0 + row) * K + kt + gc * 8),
                (__attribute__((address_space(3))) unsigned int*)(&Bs[row * BK + schunk * 8]), 16, 0, 0);
        }
        __syncthreads();
#pragma unroll
        for (int kk = 0; kk < 2; kk++) {
            bf16x8 af[4], bfr[2];
#pragma unroll
            for (int i = 0; i < 4; i++)
                af[i] = *(const bf16x8*)(&As[(i * 16 + lr) * BK + (((kk * 4 + lg) ^ (lr & 7))) * 8]);
#pragma unroll
            for (int jj = 0; jj < 2; jj++)
                bfr[jj] = *(const bf16x8*)(&Bs[(wn + jj * 16 + lr) * BK + (((kk * 4 + lg) ^ (lr & 7))) * 8]);
#pragma unroll
            for (int i = 0; i < 4; i++)
#pragma unroll
                for (int jj = 0; jj < 2; jj++)
                    acc[i][jj] = __builtin_amdgcn_mfma_f32_16x16x32_bf16(af[i], bfr[jj], acc[i][jj], 0, 0, 0);
        }
        __syncthreads();
    }

    if (region == 0) {
#pragma unroll
        for (int i = 0; i < 4; i++) {
            int rbase = m0 + i * 16 + lg * 4;
#pragma unroll
            for (int jj = 0; jj < 2; jj++) {
                int col = n0 + wn + jj * 16 + lr;
                float bvv = bq[col];
#pragma unroll
                for (int r = 0; r < 4; r++)
                    Qp[(size_t)(rbase + r) * 1024 + col] = f2bf((acc[i][jj][r] + bvv) * SCALE2);
            }
        }
    } else if (region == 1) {
#pragma unroll
        for (int i = 0; i < 4; i++) {
            int rbase = m0 + i * 16 + lg * 4;
#pragma unroll
            for (int jj = 0; jj < 2; jj++) {
                int col = n0 - 1024 + wn + jj * 16 + lr;
                float bvv = bk[col];
#pragma unroll
                for (int r = 0; r < 4; r++)
                    Kp[(size_t)(rbase + r) * 1024 + col] = f2bf(acc[i][jj][r] + bvv);
            }
        }
    } else {
        int bidx = m0 >> 11;
#pragma unroll
        for (int i = 0; i < 4; i++) {
            int s0 = (m0 & 2047) + i * 16 + lg * 4;
#pragma unroll
            for (int jj = 0; jj < 2; jj++) {
                int nv = n0 - 2048 + wn + jj * 16 + lr;
                float bvv = bv[nv];
                int hh = nv >> 6, dd = nv & 63;
                ushort4 st;
                st.x = f2bf(acc[i][jj][0] + bvv);
                st.y = f2bf(acc[i][jj][1] + bvv);
                st.z = f2bf(acc[i][jj][2] + bvv);
                st.w = f2bf(acc[i][jj][3] + bvv);
                *(ushort4*)(Vt + ((size_t)((bidx * HEADS + hh) * DH + dd)) * SEQ + s0) = st;
            }
        }
    }
}

// ---------------- O projection: NT GEMM, fp32 out ----------------
__global__ __launch_bounds__(256) void gemm_o(
    const unsigned short* __restrict__ A,
    const unsigned short* __restrict__ Bw,
    const float* __restrict__ bias,
    float* __restrict__ C,
    int M, int N, int K)
{
    constexpr int BK = 64;
    __shared__ alignas(16) unsigned short As[64 * BK];
    __shared__ alignas(16) unsigned short Bs[128 * BK];

    const int t = threadIdx.x;
    const int lane = t & 63;
    const int w = t >> 6;
    const int wn = w * 32;
    const int lr = lane & 15, lg = lane >> 4;
    const int m0 = blockIdx.x * 64, n0 = blockIdx.y * 128;

    f32x4 acc[4][2] = {};
    const int srow = t >> 3;
    const int schunk = t & 7;

    for (int kt = 0; kt < K; kt += BK) {
#pragma unroll
        for (int c = 0; c < 2; c++) {
            int row = srow + c * 32;
            int gc = schunk ^ (row & 7);
            __builtin_amdgcn_global_load_lds(
                (const __attribute__((address_space(1))) unsigned int*)(A + (size_t)(m0 + row) * K + kt + gc * 8),
                (__attribute__((address_space(3))) unsigned int*)(&As[row * BK + schunk * 8]), 16, 0, 0);
        }
#pragma unroll
        for (int c = 0; c < 4; c++) {
            int row = srow + c * 32;
            int gc = schunk ^ (row & 7);
            __builtin_amdgcn_global_load_lds(
                (const __attribute__((address_space(1))) unsigned int*)(Bw + (size_t)(n0 + row) * K + kt + gc * 8),
                (__attribute__((address_space(3))) unsigned int*)(&Bs[row * BK + schunk * 8]), 16, 0, 0);
        }
        __syncthreads();
#pragma unroll
        for (int kk = 0; kk < 2; kk++) {
            bf16x8 af[4], bfr[2];
#pragma unroll
            for (int i = 0; i < 4; i++)
                af[i] = *(const bf16x8*)(&As[(i * 16 + lr) * BK + (((kk * 4 + lg) ^ (lr & 7))) * 8]);
#pragma unroll
            for (int jj = 0; jj < 2; jj++)
                bfr[jj] = *(const bf16x8*)(&Bs[(wn + jj * 16 + lr) * BK + (((kk * 4 + lg) ^ (lr & 7))) * 8]);
#pragma unroll
            for (int i = 0; i < 4; i++)
#pragma unroll
                for (int jj = 0; jj < 2; jj++)
                    acc[i][jj] = __builtin_amdgcn_mfma_f32_16x16x32_bf16(af[i], bfr[jj], acc[i][jj], 0, 0, 0);
        }
        __syncthreads();
    }

#pragma unroll
    for (int i = 0; i < 4; i++) {
        int rbase = m0 + i * 16 + lg * 4;
#pragma unroll
        for (int jj = 0; jj < 2; jj++) {
            int col = n0 + wn + jj * 16 + lr;
            float bvv = bias[col];
#pragma unroll
            for (int r = 0; r < 4; r++)
                C[(size_t)(rbase + r) * 1024 + col] = acc[i][jj][r] + bvv;
        }
    }
}

// ---------------- causal flash attention: SPLIT-K parts, LDS-staged, counted vmcnt ----------------
// Grid 1280 = 40 jobs x 32 bh, LPT order (g = 39 - x>>5: longest parts dispatch first).
// Chunk c (128 q rows) split into S(c)=c/4+1 parts of <=8 KV-64 tiles.
// S==1 writes Ctx; S>=2 writes raw partials; combine_k merges.
// launch_bounds (256,2): do NOT force higher — VGPR squeeze spills, scratch ops count
// toward vmcnt and break the counted protocol (R10/R11 root cause).
__global__ __launch_bounds__(256, 2) void attn_k(
    const unsigned short* __restrict__ Qp,
    const unsigned short* __restrict__ Kp,
    const unsigned short* __restrict__ Vt,
    unsigned short* __restrict__ Ctx,
    unsigned short* __restrict__ pO,     // [32 bh][36 slots][128 q][64 d] bf16 (raw O)
    float2* __restrict__ pML)            // [32 bh][36 slots][128 q] (m, l)
{
    __shared__ alignas(16) unsigned char ldsb[2 * 16384];   // [buf][K 8KB | V 8KB]

    const int lane = threadIdx.x & 63;
    const int w = threadIdx.x >> 6;          // 0..3
    const int x = blockIdx.x;
    const int bh = x & 31;
    const int g = 39 - (x >> 5);             // LPT: long parts first
    int c, p, S;
    if (g < 4)       { c = g;                    p = 0;            S = 1; }
    else if (g < 12) { c = 4 + ((g - 4) >> 1);   p = (g - 4) & 1;  S = 2; }
    else if (g < 24) { c = 8 + (g - 12) / 3;     p = (g - 12) % 3; S = 3; }
    else             { c = 12 + ((g - 24) >> 2); p = (g - 24) & 3; S = 4; }
    const int nb = 2 * c + 2;
    const int len0 = (nb + S - 1) / S;
    const int start = p * len0;
    const int len = min(len0, nb - start);

    const int b = bh >> 4, h = bh & 15;
    const int q0 = c * 128;
    const int lq = lane & 31;
    const int hi = lane >> 5;
    const int qq = q0 + w * 32 + lq;
    const int my_nb = (q0 + 32 * w + 95) >> 6;   // global causal tile bound for this wave
    const int qmin = q0 + 32 * w;                // wave-uniform smallest q row
    constexpr float THR = 11.5f;

    // Q via asm loads + full drain: compiler's VMEM FIFO then tracks ONLY staging loads
    bf16x8 Qf[4];
    {
        u32x4 qtmp[4];
        const unsigned short* qbp = Qp + (size_t)(b * SEQ + qq) * DM + h * DH + hi * 8;
#pragma unroll
        for (int d = 0; d < 4; d++) GLOAD(qtmp[d], qbp + d * 16);
        asm volatile("s_waitcnt vmcnt(0)" ::: "memory");
        __builtin_amdgcn_sched_barrier(0);
#pragma unroll
        for (int d = 0; d < 4; d++) Qf[d] = __builtin_bit_cast(bf16x8, qtmp[d]);
    }

    // staging source addresses (pre-swizzled involution, rule 21)
    const int colx = (((lane & 7) ^ (lane >> 3)) << 4);
    const char* kg[2];
    const char* vg[2];
#pragma unroll
    for (int u = 0; u < 2; u++) {
        int s = 2 * w + u;
        int row = 8 * s + (lane >> 3);
        kg[u] = (const char*)Kp + (((size_t)(b * SEQ + row) * DM + h * DH) * 2) + colx;
        vg[u] = (const char*)Vt + ((((size_t)(b * HEADS + h) * DH + row) * SEQ) * 2) + colx;
    }
    const int kxor = (lq & 7) << 4;

    auto stage = [&](int buf, int t) {
        int kboff_k = t * (64 * DM * 2);    // K advances 64 rows
        int kboff_v = t * 128;              // V advances 64 kv cols (bytes)
#pragma unroll
        for (int u = 0; u < 2; u++) {
            int s = 2 * w + u;
            __builtin_amdgcn_global_load_lds(
                (const __attribute__((address_space(1))) unsigned int*)(kg[u] + kboff_k),
                (__attribute__((address_space(3))) unsigned int*)(&ldsb[buf * 16384 + s * 1024 + lane * 16]), 16, 0, 0);
            __builtin_amdgcn_global_load_lds(
                (const __attribute__((address_space(1))) unsigned int*)(vg[u] + kboff_v),
                (__attribute__((address_space(3))) unsigned int*)(&ldsb[buf * 16384 + 8192 + s * 1024 + lane * 16]), 16, 0, 0);
        }
    };

    f32x16 o0 = {}, o1 = {};
    float m_run = -1e30f, l_run = 0.f;
    const int qmh0 = qq - 4 * hi;

    stage(0, start);   // prologue: 4 loads/wave in flight

    for (int it = 0; it < len; it++) {
        const int t = start + it;
        const int cur = it & 1;
        if (it + 1 < len) {
            stage(cur ^ 1, t + 1);
            asm volatile("s_waitcnt vmcnt(4)" ::: "memory");
        } else {
            asm volatile("s_waitcnt vmcnt(0)" ::: "memory");
        }
        __builtin_amdgcn_sched_barrier(0);
        __builtin_amdgcn_s_barrier();      // all waves' stage(t) landed -> buf cur valid

        if (t < my_nb) {
            const unsigned char* Kb = &ldsb[cur * 16384];
            const unsigned char* Vb = Kb + 8192;
            const int kb = t * 64;

            bf16x8 KA[4], KB[4], Vc[4][2];
#pragma unroll
            for (int d = 0; d < 4; d++) {
                int col = (d * 32 + hi * 16) ^ kxor;
                KA[d] = *(const bf16x8*)(Kb + lq * 128 + col);
                KB[d] = *(const bf16x8*)(Kb + (lq + 32) * 128 + col);
            }
#pragma unroll
            for (int s = 0; s < 4; s++)
#pragma unroll
                for (int dt = 0; dt < 2; dt++)
                    Vc[s][dt] = *(const bf16x8*)(Vb + (dt * 32 + lq) * 128 + ((s * 32 + hi * 16) ^ kxor));

            f32x16 sa0 = {}, sa1 = {};
            __builtin_amdgcn_s_setprio(1);
#pragma unroll
            for (int d = 0; d < 4; d++) {
                sa0 = __builtin_amdgcn_mfma_f32_32x32x16_bf16(KA[d], Qf[d], sa0, 0, 0, 0);
                sa1 = __builtin_amdgcn_mfma_f32_32x32x16_bf16(KB[d], Qf[d], sa1, 0, 0, 0);
            }
            __builtin_amdgcn_s_setprio(0);

            // causal mask only on diagonal tiles (wave-uniform branch)
            if (kb + 63 > qmin) {
                const int qmh = qmh0 - kb;
#pragma unroll
                for (int r = 0; r < 16; r++) {
                    int kvl = (r & 3) + 8 * (r >> 2);
                    sa0[r] = (kvl <= qmh) ? sa0[r] : -1e30f;
                    sa1[r] = (kvl + 32 <= qmh) ? sa1[r] : -1e30f;
                }
            }
            float mx[16];
#pragma unroll
            for (int r = 0; r < 16; r++) mx[r] = fmaxf(sa0[r], sa1[r]);
#pragma unroll
            for (int r = 0; r < 8; r++) mx[r] = fmaxf(mx[r], mx[r + 8]);
#pragma unroll
            for (int r = 0; r < 4; r++) mx[r] = fmaxf(mx[r], mx[r + 4]);
            mx[0] = fmaxf(mx[0], mx[2]);
            mx[1] = fmaxf(mx[1], mx[3]);
            float mloc = fmaxf(mx[0], mx[1]);
            mloc = fmaxf(mloc, __shfl_xor(mloc, 32));

            if (!__all(mloc - m_run <= THR)) {
                float m_new = fmaxf(m_run, mloc);
                float sf = __builtin_amdgcn_exp2f(m_run - m_new);
                l_run *= sf;
#pragma unroll
                for (int r = 0; r < 16; r++) { o0[r] *= sf; o1[r] *= sf; }
                m_run = m_new;
            }

            float p0v[16], p1v[16];
#pragma unroll
            for (int r = 0; r < 16; r++) {
                p0v[r] = __builtin_amdgcn_exp2f(sa0[r] - m_run);
                p1v[r] = __builtin_amdgcn_exp2f(sa1[r] - m_run);
            }
            float s4[8];
#pragma unroll
            for (int r = 0; r < 8; r++) s4[r] = (p0v[r] + p0v[r + 8]) + (p1v[r] + p1v[r + 8]);
#pragma unroll
            for (int r = 0; r < 4; r++) s4[r] += s4[r + 4];
            float ps = (s4[0] + s4[1]) + (s4[2] + s4[3]);
            ps += __shfl_xor(ps, 32);
            l_run += ps;

            unsigned c0[8], c1[8];
#pragma unroll
            for (int ii = 0; ii < 8; ii++) {
                unsigned pk;
                asm("v_cvt_pk_bf16_f32 %0, %1, %2" : "=v"(pk) : "v"(p0v[2 * ii]), "v"(p0v[2 * ii + 1]));
                c0[ii] = pk;
                asm("v_cvt_pk_bf16_f32 %0, %1, %2" : "=v"(pk) : "v"(p1v[2 * ii]), "v"(p1v[2 * ii + 1]));
                c1[ii] = pk;
            }
            bf16x8 Pb[4];
            {
                u32x2 r02 = __builtin_amdgcn_permlane32_swap(c0[0], c0[2], false, false);
                u32x2 r13 = __builtin_amdgcn_permlane32_swap(c0[1], c0[3], false, false);
                u32x2 r46 = __builtin_amdgcn_permlane32_swap(c0[4], c0[6], false, false);
                u32x2 r57 = __builtin_amdgcn_permlane32_swap(c0[5], c0[7], false, false);
                u32x4 w0 = {r02.x, r13.x, r02.y, r13.y};
                u32x4 w1 = {r46.x, r57.x, r46.y, r57.y};
                Pb[0] = __builtin_bit_cast(bf16x8, w0);
                Pb[1] = __builtin_bit_cast(bf16x8, w1);
            }
            {
                u32x2 r02 = __builtin_amdgcn_permlane32_swap(c1[0], c1[2], false, false);
                u32x2 r13 = __builtin_amdgcn_permlane32_swap(c1[1], c1[3], false, false);
                u32x2 r46 = __builtin_amdgcn_permlane32_swap(c1[4], c1[6], false, false);
                u32x2 r57 = __builtin_amdgcn_permlane32_swap(c1[5], c1[7], false, false);
                u32x4 w0 = {r02.x, r13.x, r02.y, r13.y};
                u32x4 w1 = {r46.x, r57.x, r46.y, r57.y};
                Pb[2] = __builtin_bit_cast(bf16x8, w0);
                Pb[3] = __builtin_bit_cast(bf16x8, w1);
            }

            __builtin_amdgcn_s_setprio(1);
#pragma unroll
            for (int s = 0; s < 4; s++) {
                o0 = __builtin_amdgcn_mfma_f32_32x32x16_bf16(Vc[s][0], Pb[s], o0, 0, 0, 0);
                o1 = __builtin_amdgcn_mfma_f32_32x32x16_bf16(Vc[s][1], Pb[s], o1, 0, 0, 0);
            }
            __builtin_amdgcn_s_setprio(0);
        }
        __builtin_amdgcn_s_barrier();      // all reads of buf cur done before next overwrite
    }

    if (S == 1) {
        float inv = 1.0f / l_run;
        unsigned short* cb = Ctx + (size_t)(b * SEQ + qq) * DM + h * DH + hi * 4;
#pragma unroll
        for (int gg = 0; gg < 4; gg++) {
            ushort4 s0, s1;
            s0.x = f2bf(o0[4 * gg + 0] * inv); s0.y = f2bf(o0[4 * gg + 1] * inv);
            s0.z = f2bf(o0[4 * gg + 2] * inv); s0.w = f2bf(o0[4 * gg + 3] * inv);
            s1.x = f2bf(o1[4 * gg + 0] * inv); s1.y = f2bf(o1[4 * gg + 1] * inv);
            s1.z = f2bf(o1[4 * gg + 2] * inv); s1.w = f2bf(o1[4 * gg + 3] * inv);
            *(ushort4*)(cb + gg * 8) = s0;
            *(ushort4*)(cb + 32 + gg * 8) = s1;
        }
        return;
    }

    // ---- split part: write raw partial (O bf16, m, l); combine_k merges after ----
    const int slot = g - 4;                       // 0..35
    const int qrow = w * 32 + lq;
    unsigned short* pb = pO + ((size_t)(bh * 36 + slot) * 8192) + qrow * 64 + hi * 4;
#pragma unroll
    for (int gg = 0; gg < 4; gg++) {
        ushort4 s0, s1;
        s0.x = f2bf(o0[4 * gg + 0]); s0.y = f2bf(o0[4 * gg + 1]);
        s0.z = f2bf(o0[4 * gg + 2]); s0.w = f2bf(o0[4 * gg + 3]);
        s1.x = f2bf(o1[4 * gg + 0]); s1.y = f2bf(o1[4 * gg + 1]);
        s1.z = f2bf(o1[4 * gg + 2]); s1.w = f2bf(o1[4 * gg + 3]);
        *(ushort4*)(pb + gg * 8) = s0;
        *(ushort4*)(pb + 32 + gg * 8) = s1;
    }
    if (hi == 0)
        pML[(size_t)(bh * 36 + slot) * 128 + qrow] = make_float2(m_run, l_run);
}

// ---------------- split-K combine: Ctx[c=4..15] = weighted sum of partials ----------------
__global__ __launch_bounds__(256) void combine_k(
    const unsigned short* __restrict__ pO,
    const float2* __restrict__ pML,
    unsigned short* __restrict__ Ctx)
{
    const int x = blockIdx.x;
    const int bh = x & 31;
    const int c = (x >> 5) + 4;              // 4..15
    const int S = (c >> 2) + 1;              // 2..4
    int slot0;
    if (c < 8)       slot0 = 2 * (c - 4);
    else if (c < 12) slot0 = 8 + 3 * (c - 8);
    else             slot0 = 20 + 4 * (c - 12);
    const int b = bh >> 4, h = bh & 15;

    const int q = threadIdx.x >> 1;          // 0..127
    const int d0 = (threadIdx.x & 1) * 32;

    float m[4], l[4], wgt[4];
    float M = -1e30f;
#pragma unroll
    for (int i = 0; i < 4; i++) {
        if (i < S) {
            float2 ml = pML[(size_t)(bh * 36 + slot0 + i) * 128 + q];
            m[i] = ml.x; l[i] = ml.y;
            M = fmaxf(M, m[i]);
        }
    }
    float L = 0.f;
#pragma unroll
    for (int i = 0; i < 4; i++) {
        if (i < S) {
            wgt[i] = __builtin_amdgcn_exp2f(m[i] - M);
            L += l[i] * wgt[i];
        }
    }
    float invL = 1.0f / L;
#pragma unroll
    for (int i = 0; i < 4; i++) if (i < S) wgt[i] *= invL;

    unsigned short* cb = Ctx + (size_t)(b * SEQ + c * 128 + q) * DM + h * DH + d0;
#pragma unroll
    for (int dd = 0; dd < 32; dd += 8) {
        float acc[8] = {};
#pragma unroll
        for (int i = 0; i < 4; i++) {
            if (i < S) {
                const unsigned short* pp = pO + ((size_t)(bh * 36 + slot0 + i) * 8192) + q * 64 + d0 + dd;
                bf16x8 v = *(const bf16x8*)pp;
#pragma unroll
                for (int e = 0; e < 8; e++)
                    acc[e] += wgt[i] * bf2f((unsigned short)v[e]);
            }
        }
        ushort4 s0, s1;
        s0.x = f2bf(acc[0]); s0.y = f2bf(acc[1]); s0.z = f2bf(acc[2]); s0.w = f2bf(acc[3]);
        s1.x = f2bf(acc[4]); s1.y = f2bf(acc[5]); s1.z = f2bf(acc[6]); s1.w = f2bf(acc[7]);
        *(ushort4*)(cb + dd) = s0;
        *(ushort4*)(cb + dd + 4) = s1;
    }
}

extern "C" void kernel_launch(void* const* d_in, const int* in_sizes, int n_in,
                              void* d_out, int out_size, void* d_ws, size_t ws_size,
                              hipStream_t stream)
{
    const float* query = (const float*)d_in[0];
    const float* keyv  = (const float*)d_in[1];
    const float* Wq = (const float*)d_in[2];
    const float* bq = (const float*)d_in[3];
    const float* Wk = (const float*)d_in[4];
    const float* bk = (const float*)d_in[5];
    const float* Wv = (const float*)d_in[6];
    const float* bv = (const float*)d_in[7];
    const float* Wo = (const float*)d_in[8];
    const float* bo = (const float*)d_in[9];
    float* out = (float*)d_out;

    const int M = BATCH * SEQ;
    char* ws = (char*)d_ws;
    size_t off = 0;
    auto alloc = [&](size_t elems) { unsigned short* p = (unsigned short*)(ws + off); off += elems * 2; return p; };
    unsigned short* qb  = alloc((size_t)M * DM);    // dead after proj -> reused as pO
    unsigned short* kvb = alloc((size_t)M * DM);    // dead after proj -> reused as pO
    unsigned short* wqb = alloc((size_t)DM * DM);   // wqb/wkb/wvb MUST stay contiguous (merged QKV weight block)
    unsigned short* wkb = alloc((size_t)DM * DM);
    unsigned short* wvb = alloc((size_t)DM * DM);   // dead after proj -> reused as pML
    unsigned short* wob = alloc((size_t)DM * DM);
    unsigned short* Qp  = alloc((size_t)M * DM);
    unsigned short* Kp  = alloc((size_t)M * DM);
    unsigned short* Vt  = alloc((size_t)M * DM);
    unsigned short* Ctx = alloc((size_t)M * DM);

    // split-K scratch overlaid on buffers that are dead by attn time
    unsigned short* pO  = (unsigned short*)(ws + 0);            // 18,874,368 B (qb+kvb+wqb exactly)
    float2*         pML = (float2*)(ws + 20971520);             // wvb start, 1.125 MB

    cast_all_k<<<6144, 256, 0, stream>>>(query, keyv, Wq, Wk, Wv, Wo,
                                         qb, kvb, wqb, wkb, wvb, wob);

    proj_qkv<<<dim3(M / 64, 24), 256, 0, stream>>>(qb, kvb, wqb, bq, bk, bv, Qp, Kp, Vt);

    attn_k<<<dim3(1280), 256, 0, stream>>>(Qp, Kp, Vt, Ctx, pO, pML);
    combine_k<<<dim3(384), 256, 0, stream>>>(pO, pML, Ctx);

    gemm_o<<<dim3(M / 64, 8), 256, 0, stream>>>(Ctx, wob, bo, out, M, DM, DM);
}